// Round 1
// baseline (4203.794 us; speedup 1.0000x reference)
//
#include <hip/hip_runtime.h>
#include <math.h>

__device__ __forceinline__ float gelu_f(float x) {
  const float c0 = 0.7978845608028654f;
  return 0.5f * x * (1.0f + tanhf(c0 * (x + 0.044715f * x * x * x)));
}

// ---------------- tiled f32 GEMM: C[M,N] = A[M,K] @ B[K,N] (+bias, gelu, acc) ----
template<bool ACC, bool BIAS, bool GELU>
__global__ __launch_bounds__(256)
void gemm_k(const float* __restrict__ A, const float* __restrict__ B,
            const float* __restrict__ bias, float* __restrict__ C,
            int M, int N, int K)
{
  __shared__ float As[16][132];
  __shared__ float Bs[16][132];
  const int tid = threadIdx.x;
  const int tx = tid & 15, ty = tid >> 4;
  const int bm = blockIdx.x * 128, bn = blockIdx.y * 128;
  float acc[8][8];
#pragma unroll
  for (int i = 0; i < 8; ++i)
#pragma unroll
    for (int j = 0; j < 8; ++j) acc[i][j] = 0.f;

  const int ar = tid >> 1;        // 0..127
  const int ac = (tid & 1) * 8;   // 0 or 8
  const int br = tid >> 4;        // 0..15
  const int bc = (tid & 15) * 8;  // 0..120

  for (int k0 = 0; k0 < K; k0 += 16) {
    {
      float av[8] = {0,0,0,0,0,0,0,0};
      if (bm + ar < M) {
        const float* ap = A + (size_t)(bm + ar) * K + (k0 + ac);
        float4 a0 = *(const float4*)ap;
        float4 a1 = *(const float4*)(ap + 4);
        av[0]=a0.x; av[1]=a0.y; av[2]=a0.z; av[3]=a0.w;
        av[4]=a1.x; av[5]=a1.y; av[6]=a1.z; av[7]=a1.w;
      }
#pragma unroll
      for (int i = 0; i < 8; ++i) As[ac + i][ar] = av[i];
    }
    {
      float bv[8] = {0,0,0,0,0,0,0,0};
      const float* bp = B + (size_t)(k0 + br) * N + (bn + bc);
      if (bn + bc + 7 < N) {
        float4 b0 = *(const float4*)bp;
        float4 b1 = *(const float4*)(bp + 4);
        bv[0]=b0.x; bv[1]=b0.y; bv[2]=b0.z; bv[3]=b0.w;
        bv[4]=b1.x; bv[5]=b1.y; bv[6]=b1.z; bv[7]=b1.w;
      } else {
#pragma unroll
        for (int i = 0; i < 8; ++i) { if (bn + bc + i < N) bv[i] = bp[i]; }
      }
#pragma unroll
      for (int i = 0; i < 8; ++i) Bs[br][bc + i] = bv[i];
    }
    __syncthreads();
#pragma unroll
    for (int kk = 0; kk < 16; ++kk) {
      float a[8], b[8];
      float4 t0 = *(const float4*)&As[kk][ty * 8];
      float4 t1 = *(const float4*)&As[kk][ty * 8 + 4];
      float4 u0 = *(const float4*)&Bs[kk][tx * 8];
      float4 u1 = *(const float4*)&Bs[kk][tx * 8 + 4];
      a[0]=t0.x;a[1]=t0.y;a[2]=t0.z;a[3]=t0.w;a[4]=t1.x;a[5]=t1.y;a[6]=t1.z;a[7]=t1.w;
      b[0]=u0.x;b[1]=u0.y;b[2]=u0.z;b[3]=u0.w;b[4]=u1.x;b[5]=u1.y;b[6]=u1.z;b[7]=u1.w;
#pragma unroll
      for (int i = 0; i < 8; ++i)
#pragma unroll
        for (int j = 0; j < 8; ++j)
          acc[i][j] = fmaf(a[i], b[j], acc[i][j]);
    }
    __syncthreads();
  }
#pragma unroll
  for (int i = 0; i < 8; ++i) {
    int row = bm + ty * 8 + i;
    if (row >= M) continue;
    int colg = bn + tx * 8;
    float* cp = C + (size_t)row * N + colg;
    float o[8];
#pragma unroll
    for (int j = 0; j < 8; ++j) {
      float val = acc[i][j];
      if (BIAS) { int cc = colg + j; val += (cc < N) ? bias[cc] : 0.f; }
      if (GELU) val = gelu_f(val);
      o[j] = val;
    }
    if (colg + 7 < N) {
      if (ACC) {
        float4 c0 = *(float4*)cp;
        float4 c1 = *(float4*)(cp + 4);
        o[0]+=c0.x; o[1]+=c0.y; o[2]+=c0.z; o[3]+=c0.w;
        o[4]+=c1.x; o[5]+=c1.y; o[6]+=c1.z; o[7]+=c1.w;
      }
      *(float4*)cp = make_float4(o[0],o[1],o[2],o[3]);
      *(float4*)(cp + 4) = make_float4(o[4],o[5],o[6],o[7]);
    } else {
#pragma unroll
      for (int j = 0; j < 8; ++j) {
        int cc = colg + j;
        if (cc < N) { float val = o[j]; if (ACC) val += cp[j]; cp[j] = val; }
      }
    }
  }
}

// ---------------- We transpose (64x256 -> 256x64) ----------------
__global__ void transpose_we_k(const float* __restrict__ We, float* __restrict__ WeT) {
  int f = threadIdx.x; // 0..255
  for (int c = 0; c < 64; ++c) WeT[(size_t)f * 64 + c] = We[(size_t)c * 256 + f];
}

// ---------------- T[n,h,c] = sum_d q[n,h*32+d] * We[c,h*32+d] -----------------
__global__ __launch_bounds__(256)
void tproj_k(const float* __restrict__ q, const float* __restrict__ WeT,
             float* __restrict__ T, int Nn)
{
  const int wv = (blockIdx.x * blockDim.x + threadIdx.x) >> 6;
  if (wv >= Nn) return;
  const int lane = threadIdx.x & 63;
  const int g = lane >> 3, p = lane & 7;
  float4 q4 = *(const float4*)(q + (size_t)wv * 256 + lane * 4);
  float qa[4] = {q4.x, q4.y, q4.z, q4.w};
  float t[8] = {0,0,0,0,0,0,0,0};
#pragma unroll
  for (int d = 0; d < 32; ++d) {
    float qd = __shfl(qa[d & 3], g * 8 + (d >> 2), 64);
    const float* wpp = WeT + (size_t)(g * 32 + d) * 64 + p * 8;
    float4 w0 = *(const float4*)wpp;
    float4 w1 = *(const float4*)(wpp + 4);
    t[0] = fmaf(qd, w0.x, t[0]); t[1] = fmaf(qd, w0.y, t[1]);
    t[2] = fmaf(qd, w0.z, t[2]); t[3] = fmaf(qd, w0.w, t[3]);
    t[4] = fmaf(qd, w1.x, t[4]); t[5] = fmaf(qd, w1.y, t[5]);
    t[6] = fmaf(qd, w1.z, t[6]); t[7] = fmaf(qd, w1.w, t[7]);
  }
  float* tp = T + (size_t)wv * 512 + g * 64 + p * 8;
  *(float4*)tp = make_float4(t[0], t[1], t[2], t[3]);
  *(float4*)(tp + 4) = make_float4(t[4], t[5], t[6], t[7]);
}

// ---------------- per-dst online-softmax edge aggregation ----------------
__global__ __launch_bounds__(256)
void edge_attn_k(const int* __restrict__ offs, const int* __restrict__ sorted,
                 const int* __restrict__ srcidx, const float* __restrict__ ea,
                 const float* __restrict__ T, const float* __restrict__ q,
                 const float* __restrict__ k, const float* __restrict__ v,
                 const float* __restrict__ We, float* __restrict__ msg, int Nn)
{
  const int wv = (blockIdx.x * blockDim.x + threadIdx.x) >> 6;
  if (wv >= Nn) return;
  const int lane = threadIdx.x & 63;
  const int g = lane >> 3, p = lane & 7;
  const float scale = 0.17677669529663687f; // 1/sqrt(32)
  const float4 q4 = *(const float4*)(q + (size_t)wv * 256 + lane * 4);
  const float4 Ta = *(const float4*)(T + (size_t)wv * 512 + g * 64 + p * 8);
  const float4 Tc = *(const float4*)(T + (size_t)wv * 512 + g * 64 + p * 8 + 4);
  float m = -INFINITY, den = 0.f;
  float accx = 0.f, accy = 0.f, accz = 0.f, accw = 0.f;
  float G[8] = {0,0,0,0,0,0,0,0};
  const int e0 = offs[wv], e1 = offs[wv + 1];
  for (int j = e0; j < e1; ++j) {
    const int eid = sorted[j];
    const int src = srcidx[eid];
    const float eav = ea[(size_t)eid * 64 + lane];
    const float4 k4 = *(const float4*)(k + (size_t)src * 256 + lane * 4);
    const float4 v4 = *(const float4*)(v + (size_t)src * 256 + lane * 4);
    float t8[8];
#pragma unroll
    for (int i = 0; i < 8; ++i) t8[i] = __shfl(eav, p * 8 + i, 64);
    float part = q4.x*k4.x + q4.y*k4.y + q4.z*k4.z + q4.w*k4.w;
    part += t8[0]*Ta.x + t8[1]*Ta.y + t8[2]*Ta.z + t8[3]*Ta.w;
    part += t8[4]*Tc.x + t8[5]*Tc.y + t8[6]*Tc.z + t8[7]*Tc.w;
    part += __shfl_xor(part, 1, 64);
    part += __shfl_xor(part, 2, 64);
    part += __shfl_xor(part, 4, 64);
    const float s = part * scale;
    const float mn = fmaxf(m, s);
    const float corr = __expf(m - mn);  // exp(-inf)=0 on first edge
    const float w = __expf(s - mn);
    m = mn;
    den = den * corr + w;
    accx = fmaf(w, v4.x, accx * corr);
    accy = fmaf(w, v4.y, accy * corr);
    accz = fmaf(w, v4.z, accz * corr);
    accw = fmaf(w, v4.w, accw * corr);
#pragma unroll
    for (int i = 0; i < 8; ++i) G[i] = fmaf(w, t8[i], G[i] * corr);
  }
  // e-message: sum_c G[head(lane)][c] * We[c][4*lane..4*lane+3]
  float exx = 0.f, eyy = 0.f, ezz = 0.f, eww = 0.f;
#pragma unroll
  for (int cp2 = 0; cp2 < 8; ++cp2) {
#pragma unroll
    for (int i = 0; i < 8; ++i) {
      const float Gc = __shfl(G[i], g * 8 + cp2, 64);
      const int c = cp2 * 8 + i;
      const float4 w4 = *(const float4*)(We + (size_t)c * 256 + lane * 4);
      exx = fmaf(Gc, w4.x, exx); eyy = fmaf(Gc, w4.y, eyy);
      ezz = fmaf(Gc, w4.z, ezz); eww = fmaf(Gc, w4.w, eww);
    }
  }
  const float inv = 1.f / (den + 1e-9f);
  float4 o;
  o.x = (accx + exx) * inv; o.y = (accy + eyy) * inv;
  o.z = (accz + ezz) * inv; o.w = (accw + eww) * inv;
  *(float4*)(msg + (size_t)wv * 256 + lane * 4) = o;
}

// ---------------- residual add + LayerNorm (no affine), row=256 ----------------
__global__ __launch_bounds__(256)
void add_ln_k(float* __restrict__ x, const float* __restrict__ add, int Nn)
{
  const int wv = (blockIdx.x * blockDim.x + threadIdx.x) >> 6;
  if (wv >= Nn) return;
  const int lane = threadIdx.x & 63;
  float4 xv = *(const float4*)(x + (size_t)wv * 256 + lane * 4);
  float4 av = *(const float4*)(add + (size_t)wv * 256 + lane * 4);
  float4 y;
  y.x = xv.x + av.x; y.y = xv.y + av.y; y.z = xv.z + av.z; y.w = xv.w + av.w;
  float s = y.x + y.y + y.z + y.w;
#pragma unroll
  for (int msk = 1; msk < 64; msk <<= 1) s += __shfl_xor(s, msk, 64);
  const float mean = s * (1.f / 256.f);
  float4 d;
  d.x = y.x - mean; d.y = y.y - mean; d.z = y.z - mean; d.w = y.w - mean;
  float sq = d.x*d.x + d.y*d.y + d.z*d.z + d.w*d.w;
#pragma unroll
  for (int msk = 1; msk < 64; msk <<= 1) sq += __shfl_xor(sq, msk, 64);
  const float r = rsqrtf(sq * (1.f / 256.f) + 1e-5f);
  float4 o;
  o.x = d.x * r; o.y = d.y * r; o.z = d.z * r; o.w = d.w * r;
  *(float4*)(x + (size_t)wv * 256 + lane * 4) = o;
}

// ---------------- small utility kernels ----------------
__global__ void copy_f4_k(const float4* __restrict__ s, float4* __restrict__ d, int n4) {
  int i = blockIdx.x * blockDim.x + threadIdx.x;
  if (i < n4) d[i] = s[i];
}
__global__ void zero_i_k(int* p, int n) {
  int i = blockIdx.x * blockDim.x + threadIdx.x;
  if (i < n) p[i] = 0;
}
__global__ void copy_i_k(const int* s, int* d, int n) {
  int i = blockIdx.x * blockDim.x + threadIdx.x;
  if (i < n) d[i] = s[i];
}
__global__ void hist_k(const int* __restrict__ dst, int E, int* __restrict__ cnt) {
  int e = blockIdx.x * blockDim.x + threadIdx.x;
  if (e < E) atomicAdd(&cnt[dst[e]], 1);
}
__global__ void scatter_k(const int* __restrict__ dst, int E, int* __restrict__ cursor,
                          int* __restrict__ sorted) {
  int e = blockIdx.x * blockDim.x + threadIdx.x;
  if (e < E) {
    int pos = atomicAdd(&cursor[dst[e]], 1);
    sorted[pos] = e;
  }
}
__global__ __launch_bounds__(256)
void scan_k(const int* __restrict__ cnt, int* __restrict__ offs, int Nn)
{
  __shared__ int sums[256];
  const int t = threadIdx.x;
  const int chunk = (Nn + 255) / 256;
  const int base = t * chunk;
  int s = 0;
  for (int i = 0; i < chunk; ++i) {
    int idx = base + i;
    if (idx < Nn) s += cnt[idx];
  }
  sums[t] = s;
  __syncthreads();
  for (int off = 1; off < 256; off <<= 1) {
    int val = (t >= off) ? sums[t - off] : 0;
    __syncthreads();
    sums[t] += val;
    __syncthreads();
  }
  int run = (t == 0) ? 0 : sums[t - 1];
  for (int i = 0; i < chunk; ++i) {
    int idx = base + i;
    if (idx < Nn) { offs[idx] = run; run += cnt[idx]; }
  }
  if (t == 255) offs[Nn] = run;
}

// ---------------- host orchestration ----------------
extern "C" void kernel_launch(void* const* d_in, const int* in_sizes, int n_in,
                              void* d_out, int out_size, void* d_ws, size_t ws_size,
                              hipStream_t stream)
{
  (void)n_in; (void)ws_size;
  const float* afl = (const float*)d_in[0];
  const float* afr = (const float*)d_in[1];
  const float* eaA[4] = {(const float*)d_in[2], (const float*)d_in[3],
                         (const float*)d_in[4], (const float*)d_in[5]};
  const int* eiA[4] = {(const int*)d_in[6], (const int*)d_in[7],
                       (const int*)d_in[8], (const int*)d_in[9]};
  const float* Wq  = (const float*)d_in[10];
  const float* Wk  = (const float*)d_in[11];
  const float* Wv  = (const float*)d_in[12];
  const float* We  = (const float*)d_in[13];
  const float* Wo  = (const float*)d_in[14];
  const float* fw1 = (const float*)d_in[15];
  const float* fb1 = (const float*)d_in[16];
  const float* fw2 = (const float*)d_in[17];
  const float* fb2 = (const float*)d_in[18];
  const float* hw1 = (const float*)d_in[19];
  const float* hb1 = (const float*)d_in[20];
  const float* hw2 = (const float*)d_in[21];
  const float* hb2 = (const float*)d_in[22];

  const int Nn = in_sizes[0] / 256;
  const int Esz[4] = {in_sizes[2] / 64, in_sizes[3] / 64, in_sizes[4] / 64, in_sizes[5] / 64};
  const int Mh = out_size / 14;           // rows per output head
  const int astart = Nn - Mh;             // action_start
  float* out = (float*)d_out;

  char* wsp = (char*)d_ws;
  auto alloc = [&](size_t bytes) -> void* {
    void* p = (void*)wsp;
    wsp += (bytes + 255) & ~(size_t)255;
    return p;
  };
  const size_t n256b = (size_t)Nn * 256 * sizeof(float);
  float* xl   = (float*)alloc(n256b);
  float* xr   = (float*)alloc(n256b);
  float* aggl = (float*)alloc(n256b);
  float* aggr = (float*)alloc(n256b);
  float* qb   = (float*)alloc(n256b);
  float* kb   = (float*)alloc(n256b);
  float* vb   = (float*)alloc(n256b);
  float* msgb = (float*)alloc(n256b);
  float* Tb   = (float*)alloc((size_t)Nn * 512 * sizeof(float)); // also FFN hidden
  float* WeT  = (float*)alloc(256 * 64 * sizeof(float));
  int* offsA[4]; int* sortA[4];
  for (int s = 0; s < 4; ++s) {
    offsA[s] = (int*)alloc((size_t)(Nn + 1) * sizeof(int));
    sortA[s] = (int*)alloc((size_t)Esz[s] * sizeof(int));
  }
  int* cursor = (int*)alloc((size_t)Nn * sizeof(int));

  const dim3 B256(256);
  const int wgNodes = (Nn * 64 + 255) / 256;   // one wave per node

  // init xl / xr
  {
    int n4 = Nn * 64;
    copy_f4_k<<<dim3((n4 + 255) / 256), B256, 0, stream>>>((const float4*)afl, (float4*)xl, n4);
    copy_f4_k<<<dim3((n4 + 255) / 256), B256, 0, stream>>>((const float4*)afr, (float4*)xr, n4);
  }
  // build CSR for the 4 edge sets
  for (int s = 0; s < 4; ++s) {
    const int E = Esz[s];
    zero_i_k<<<dim3((Nn + 255) / 256), B256, 0, stream>>>(cursor, Nn);
    hist_k<<<dim3((E + 255) / 256), B256, 0, stream>>>(eiA[s] + E, E, cursor);
    scan_k<<<1, B256, 0, stream>>>(cursor, offsA[s], Nn);
    copy_i_k<<<dim3((Nn + 255) / 256), B256, 0, stream>>>(offsA[s], cursor, Nn);
    scatter_k<<<dim3((E + 255) / 256), B256, 0, stream>>>(eiA[s] + E, E, cursor, sortA[s]);
  }

  auto gemm = [&](const float* A, const float* Bm, const float* bias, float* C,
                  int M, int N, int K, bool acc, bool biasf, bool gelu) {
    dim3 g((M + 127) / 128, (N + 127) / 128);
    if (acc)        gemm_k<true,  false, false><<<g, B256, 0, stream>>>(A, Bm, bias, C, M, N, K);
    else if (biasf && gelu)  gemm_k<false, true, true ><<<g, B256, 0, stream>>>(A, Bm, bias, C, M, N, K);
    else if (biasf)          gemm_k<false, true, false><<<g, B256, 0, stream>>>(A, Bm, bias, C, M, N, K);
    else                     gemm_k<false, false,false><<<g, B256, 0, stream>>>(A, Bm, bias, C, M, N, K);
  };

  auto run_attn = [&](int l, int i, int s, const float* xq, const float* xk,
                      float* agg, bool acc) {
    const size_t wOff  = (size_t)(l * 4 + i) * 256 * 256;
    const size_t weOff = (size_t)(l * 4 + i) * 64 * 256;
    gemm(xq, Wq + wOff, nullptr, qb, Nn, 256, 256, false, false, false);
    gemm(xk, Wk + wOff, nullptr, kb, Nn, 256, 256, false, false, false);
    gemm(xk, Wv + wOff, nullptr, vb, Nn, 256, 256, false, false, false);
    transpose_we_k<<<dim3(1), B256, 0, stream>>>(We + weOff, WeT);
    tproj_k<<<dim3(wgNodes), B256, 0, stream>>>(qb, WeT, Tb, Nn);
    edge_attn_k<<<dim3(wgNodes), B256, 0, stream>>>(offsA[s], sortA[s], eiA[s], eaA[s],
                                                    Tb, qb, kb, vb, We + weOff, msgb, Nn);
    gemm(msgb, Wo + wOff, nullptr, agg, Nn, 256, 256, acc, false, false);
  };

  const int L = 2;
  for (int l = 0; l < L; ++l) {
    // agg_l = attn(ll, W[l,0]) + attn(rl, W[l,3]); agg_r = attn(rr, W[l,1]) + attn(lr, W[l,2])
    run_attn(l, 0, 0, xl, xl, aggl, false);
    run_attn(l, 3, 3, xl, xr, aggl, true);
    run_attn(l, 1, 1, xr, xr, aggr, false);
    run_attn(l, 2, 2, xr, xl, aggr, true);
    add_ln_k<<<dim3(wgNodes), B256, 0, stream>>>(xl, aggl, Nn);
    add_ln_k<<<dim3(wgNodes), B256, 0, stream>>>(xr, aggr, Nn);
    for (int s2 = 0; s2 < 2; ++s2) {
      float* x = s2 ? xr : xl;
      const size_t w1o = (size_t)(l * 2 + s2) * 256 * 512;
      const size_t b1o = (size_t)(l * 2 + s2) * 512;
      const size_t w2o = (size_t)(l * 2 + s2) * 512 * 256;
      const size_t b2o = (size_t)(l * 2 + s2) * 256;
      gemm(x,  fw1 + w1o, fb1 + b1o, Tb, Nn, 512, 256, false, true, true);
      gemm(Tb, fw2 + w2o, fb2 + b2o, kb, Nn, 256, 512, false, true, false);
      add_ln_k<<<dim3(wgNodes), B256, 0, stream>>>(x, kb, Nn);
    }
  }
  // heads
  gemm(xl + (size_t)astart * 256, hw1, hb1, qb, Mh, 256, 256, false, true, true);
  gemm(qb, hw2, hb2, out, Mh, 7, 256, false, true, false);
  gemm(xr + (size_t)astart * 256, hw1, hb1, qb, Mh, 256, 256, false, true, true);
  gemm(qb, hw2, hb2, out + (size_t)Mh * 7, Mh, 7, 256, false, true, false);
}

// Round 2
// 2076.723 us; speedup vs baseline: 2.0242x; 2.0242x over previous
//
#include <hip/hip_runtime.h>
#include <math.h>

typedef __attribute__((ext_vector_type(8))) short short8;
typedef __attribute__((ext_vector_type(4))) float f32x4;

__device__ __forceinline__ unsigned short f2bf(float f) {
  unsigned u = __builtin_bit_cast(unsigned, f);
  u += 0x7fff + ((u >> 16) & 1);
  return (unsigned short)(u >> 16);
}
__device__ __forceinline__ float bf2f(unsigned short h) {
  unsigned u = ((unsigned)h) << 16;
  return __builtin_bit_cast(float, u);
}
__device__ __forceinline__ float gelu_f(float x) {
  const float c0 = 0.7978845608028654f;
  return 0.5f * x * (1.0f + tanhf(c0 * (x + 0.044715f * x * x * x)));
}

// ============ bf16 MFMA GEMM: C = A(f32,[M][K]) @ B  with BT bf16 [N][K] ============
// Epilogue: col < S -> f32 Cf[row*ldf+col] (opt bias/gelu/acc); col >= S -> bf16 Cb[row*ldb+col-S]
template<bool ACC, bool BIAS, bool GELU>
__global__ __launch_bounds__(256)
void gemm_mfma_k(const float* __restrict__ A, const unsigned short* __restrict__ BT,
                 const float* __restrict__ bias, float* __restrict__ Cf,
                 unsigned short* __restrict__ Cb,
                 int M, int N, int K, int S, int ldf, int ldb)
{
  __shared__ __align__(16) unsigned short As[128 * 32];
  __shared__ __align__(16) unsigned short Bs[128 * 32];
  const int tid = threadIdx.x;
  const int bm = blockIdx.x * 128, bn = blockIdx.y * 128;
  const int lane = tid & 63, w = tid >> 6;
  const int wr = w >> 1, wc = w & 1;
  const int l15 = lane & 15, kg = lane >> 4;
  // staging assignment: thread covers row/col sr, k-half kh (16 k each)
  const int sr = tid >> 1, kh = tid & 1;
  const float* ap = A + (size_t)(bm + sr) * K + kh * 16;
  const unsigned short* bp = BT + (size_t)(bn + sr) * K + kh * 16;
  const int ph0 = ((kh * 2 + 0) + (sr >> 1)) & 3;   // k-slot swizzle (2-way conflicts)
  const int ph1 = ((kh * 2 + 1) + (sr >> 1)) & 3;
  unsigned short* wa0 = As + sr * 32 + ph0 * 8;
  unsigned short* wa1 = As + sr * 32 + ph1 * 8;
  unsigned short* wb0 = Bs + sr * 32 + ph0 * 8;
  unsigned short* wb1 = Bs + sr * 32 + ph1 * 8;

  f32x4 acc[4][4] = {};

  for (int k0 = 0; k0 < K; k0 += 32) {
    float4 a0 = *(const float4*)(ap + k0);
    float4 a1 = *(const float4*)(ap + k0 + 4);
    float4 a2 = *(const float4*)(ap + k0 + 8);
    float4 a3 = *(const float4*)(ap + k0 + 12);
    uint4 b0 = *(const uint4*)(bp + k0);
    uint4 b1 = *(const uint4*)(bp + k0 + 8);
    short8 pa0, pa1;
    pa0[0] = (short)f2bf(a0.x); pa0[1] = (short)f2bf(a0.y);
    pa0[2] = (short)f2bf(a0.z); pa0[3] = (short)f2bf(a0.w);
    pa0[4] = (short)f2bf(a1.x); pa0[5] = (short)f2bf(a1.y);
    pa0[6] = (short)f2bf(a1.z); pa0[7] = (short)f2bf(a1.w);
    pa1[0] = (short)f2bf(a2.x); pa1[1] = (short)f2bf(a2.y);
    pa1[2] = (short)f2bf(a2.z); pa1[3] = (short)f2bf(a2.w);
    pa1[4] = (short)f2bf(a3.x); pa1[5] = (short)f2bf(a3.y);
    pa1[6] = (short)f2bf(a3.z); pa1[7] = (short)f2bf(a3.w);
    *(short8*)wa0 = pa0;
    *(short8*)wa1 = pa1;
    *(uint4*)wb0 = b0;
    *(uint4*)wb1 = b1;
    __syncthreads();
    short8 af[4], bfr[4];
#pragma unroll
    for (int m = 0; m < 4; ++m) {
      int row = wr * 64 + m * 16 + l15;
      int ph = (kg + (row >> 1)) & 3;
      af[m] = *(const short8*)(As + row * 32 + ph * 8);
    }
#pragma unroll
    for (int n = 0; n < 4; ++n) {
      int col = wc * 64 + n * 16 + l15;
      int ph = (kg + (col >> 1)) & 3;
      bfr[n] = *(const short8*)(Bs + col * 32 + ph * 8);
    }
#pragma unroll
    for (int m = 0; m < 4; ++m)
#pragma unroll
      for (int n = 0; n < 4; ++n)
        acc[m][n] = __builtin_amdgcn_mfma_f32_16x16x32_bf16(af[m], bfr[n], acc[m][n], 0, 0, 0);
    __syncthreads();
  }

#pragma unroll
  for (int m = 0; m < 4; ++m) {
#pragma unroll
    for (int n = 0; n < 4; ++n) {
      int col = bn + wc * 64 + n * 16 + l15;
      float bv = BIAS ? bias[col] : 0.f;
      f32x4 v = acc[m][n];
#pragma unroll
      for (int r2 = 0; r2 < 4; ++r2) {
        int row = bm + wr * 64 + m * 16 + kg * 4 + r2;
        float val = v[r2] + bv;
        if (GELU) val = gelu_f(val);
        if (col < S) {
          float* p = Cf + (size_t)row * ldf + col;
          if (ACC) val += *p;
          *p = val;
        } else {
          Cb[(size_t)row * ldb + (col - S)] = f2bf(val);
        }
      }
    }
  }
}

// ============ old f32 GEMM (kept for the tiny N=7 head2) ============
template<bool ACC, bool BIAS, bool GELU>
__global__ __launch_bounds__(256)
void gemm_k(const float* __restrict__ A, const float* __restrict__ B,
            const float* __restrict__ bias, float* __restrict__ C,
            int M, int N, int K)
{
  __shared__ float As[16][132];
  __shared__ float Bs[16][132];
  const int tid = threadIdx.x;
  const int tx = tid & 15, ty = tid >> 4;
  const int bm = blockIdx.x * 128, bn = blockIdx.y * 128;
  float acc[8][8];
#pragma unroll
  for (int i = 0; i < 8; ++i)
#pragma unroll
    for (int j = 0; j < 8; ++j) acc[i][j] = 0.f;
  const int ar = tid >> 1;
  const int ac = (tid & 1) * 8;
  const int br = tid >> 4;
  const int bc = (tid & 15) * 8;
  for (int k0 = 0; k0 < K; k0 += 16) {
    {
      float av[8] = {0,0,0,0,0,0,0,0};
      if (bm + ar < M) {
        const float* ap = A + (size_t)(bm + ar) * K + (k0 + ac);
        float4 a0 = *(const float4*)ap;
        float4 a1 = *(const float4*)(ap + 4);
        av[0]=a0.x; av[1]=a0.y; av[2]=a0.z; av[3]=a0.w;
        av[4]=a1.x; av[5]=a1.y; av[6]=a1.z; av[7]=a1.w;
      }
#pragma unroll
      for (int i = 0; i < 8; ++i) As[ac + i][ar] = av[i];
    }
    {
      float bv[8] = {0,0,0,0,0,0,0,0};
      const float* bp = B + (size_t)(k0 + br) * N + (bn + bc);
#pragma unroll
      for (int i = 0; i < 8; ++i) { if (bn + bc + i < N) bv[i] = bp[i]; }
#pragma unroll
      for (int i = 0; i < 8; ++i) Bs[br][bc + i] = bv[i];
    }
    __syncthreads();
#pragma unroll
    for (int kk = 0; kk < 16; ++kk) {
      float a[8], b[8];
      float4 t0 = *(const float4*)&As[kk][ty * 8];
      float4 t1 = *(const float4*)&As[kk][ty * 8 + 4];
      float4 u0 = *(const float4*)&Bs[kk][tx * 8];
      float4 u1 = *(const float4*)&Bs[kk][tx * 8 + 4];
      a[0]=t0.x;a[1]=t0.y;a[2]=t0.z;a[3]=t0.w;a[4]=t1.x;a[5]=t1.y;a[6]=t1.z;a[7]=t1.w;
      b[0]=u0.x;b[1]=u0.y;b[2]=u0.z;b[3]=u0.w;b[4]=u1.x;b[5]=u1.y;b[6]=u1.z;b[7]=u1.w;
#pragma unroll
      for (int i = 0; i < 8; ++i)
#pragma unroll
        for (int j = 0; j < 8; ++j)
          acc[i][j] = fmaf(a[i], b[j], acc[i][j]);
    }
    __syncthreads();
  }
#pragma unroll
  for (int i = 0; i < 8; ++i) {
    int row = bm + ty * 8 + i;
    if (row >= M) continue;
    int colg = bn + tx * 8;
    float* cp = C + (size_t)row * N + colg;
#pragma unroll
    for (int j = 0; j < 8; ++j) {
      int cc = colg + j;
      if (cc < N) {
        float val = acc[i][j];
        if (BIAS) val += bias[cc];
        if (GELU) val = gelu_f(val);
        if (ACC) val += cp[j];
        cp[j] = val;
      }
    }
  }
}

// ============ weight transpose+convert: out_bf16[(rowOff+n)*K + k] = in_f32[k*N + n] ============
__global__ void tc_k(const float* __restrict__ in, unsigned short* __restrict__ out,
                     int K, int N, int inStride, int outStride, int rowOff)
{
  const int mat = blockIdx.y;
  const int idx = blockIdx.x * 256 + threadIdx.x;
  if (idx >= N * K) return;
  const int n = idx / K, k = idx - n * K;
  out[(size_t)mat * outStride + (size_t)(rowOff + n) * K + k] =
      f2bf(in[(size_t)mat * inStride + (size_t)k * N + n]);
}

// ============ WeT (f32): out[f*64 + c] = We[c*256 + f], 8 mats ============
__global__ void weT_k(const float* __restrict__ We, float* __restrict__ WeT)
{
  const int mat = blockIdx.y;
  const int idx = blockIdx.x * 256 + threadIdx.x;
  if (idx >= 16384) return;
  const int f = idx >> 6, c = idx & 63;
  WeT[(size_t)mat * 16384 + (size_t)f * 64 + c] = We[(size_t)mat * 16384 + (size_t)c * 256 + f];
}

// ============ T[n,h,c] = sum_d q[n,h*32+d] * We[c,h*32+d] ============
__global__ __launch_bounds__(256)
void tproj_k(const float* __restrict__ q, const float* __restrict__ WeT,
             float* __restrict__ T, int Nn)
{
  const int wv = (blockIdx.x * blockDim.x + threadIdx.x) >> 6;
  if (wv >= Nn) return;
  const int lane = threadIdx.x & 63;
  const int g = lane >> 3, p = lane & 7;
  float4 q4 = *(const float4*)(q + (size_t)wv * 256 + lane * 4);
  float qa[4] = {q4.x, q4.y, q4.z, q4.w};
  float t[8] = {0,0,0,0,0,0,0,0};
#pragma unroll
  for (int d = 0; d < 32; ++d) {
    float qd = __shfl(qa[d & 3], g * 8 + (d >> 2), 64);
    const float* wpp = WeT + (size_t)(g * 32 + d) * 64 + p * 8;
    float4 w0 = *(const float4*)wpp;
    float4 w1 = *(const float4*)(wpp + 4);
    t[0] = fmaf(qd, w0.x, t[0]); t[1] = fmaf(qd, w0.y, t[1]);
    t[2] = fmaf(qd, w0.z, t[2]); t[3] = fmaf(qd, w0.w, t[3]);
    t[4] = fmaf(qd, w1.x, t[4]); t[5] = fmaf(qd, w1.y, t[5]);
    t[6] = fmaf(qd, w1.z, t[6]); t[7] = fmaf(qd, w1.w, t[7]);
  }
  float* tp = T + (size_t)wv * 512 + g * 64 + p * 8;
  *(float4*)tp = make_float4(t[0], t[1], t[2], t[3]);
  *(float4*)(tp + 4) = make_float4(t[4], t[5], t[6], t[7]);
}

// ============ per-dst online-softmax edge aggregation (2-edge unrolled) ============
__global__ __launch_bounds__(256)
void edge_attn_k(const int* __restrict__ offs, const int* __restrict__ sorted,
                 const int* __restrict__ srcidx, const float* __restrict__ ea,
                 const float* __restrict__ T, const float* __restrict__ q,
                 const unsigned short* __restrict__ kv, const float* __restrict__ We,
                 float* __restrict__ msg, int Nn)
{
  const int wv = (blockIdx.x * blockDim.x + threadIdx.x) >> 6;
  if (wv >= Nn) return;
  const int lane = threadIdx.x & 63;
  const int g = lane >> 3, p = lane & 7;
  const float scale = 0.17677669529663687f;
  const float4 q4 = *(const float4*)(q + (size_t)wv * 256 + lane * 4);
  const float* Trow = T + (size_t)wv * 512 + g * 64 + p * 8;
  const float4 Ta = *(const float4*)Trow;
  const float4 Tc = *(const float4*)(Trow + 4);
  float m = -INFINITY, den = 0.f;
  float ax = 0.f, ay = 0.f, az = 0.f, aw = 0.f;
  float G[8] = {0,0,0,0,0,0,0,0};
  const int e0 = offs[wv], e1 = offs[wv + 1];
  for (int j = e0; j < e1; j += 2) {
    const bool hasB = (j + 1) < e1;
    const int eidA = sorted[j];
    const int eidB = sorted[hasB ? j + 1 : j];
    const int srcA = srcidx[eidA];
    const int srcB = srcidx[eidB];
    const float4 eA0 = *(const float4*)(ea + (size_t)eidA * 64 + p * 8);
    const float4 eA1 = *(const float4*)(ea + (size_t)eidA * 64 + p * 8 + 4);
    const float4 eB0 = *(const float4*)(ea + (size_t)eidB * 64 + p * 8);
    const float4 eB1 = *(const float4*)(ea + (size_t)eidB * 64 + p * 8 + 4);
    const ushort4 kAu = *(const ushort4*)(kv + (size_t)srcA * 512 + lane * 4);
    const ushort4 vAu = *(const ushort4*)(kv + (size_t)srcA * 512 + 256 + lane * 4);
    const ushort4 kBu = *(const ushort4*)(kv + (size_t)srcB * 512 + lane * 4);
    const ushort4 vBu = *(const ushort4*)(kv + (size_t)srcB * 512 + 256 + lane * 4);
    float pA = q4.x * bf2f(kAu.x) + q4.y * bf2f(kAu.y) + q4.z * bf2f(kAu.z) + q4.w * bf2f(kAu.w);
    pA += eA0.x * Ta.x + eA0.y * Ta.y + eA0.z * Ta.z + eA0.w * Ta.w;
    pA += eA1.x * Tc.x + eA1.y * Tc.y + eA1.z * Tc.z + eA1.w * Tc.w;
    float pB = q4.x * bf2f(kBu.x) + q4.y * bf2f(kBu.y) + q4.z * bf2f(kBu.z) + q4.w * bf2f(kBu.w);
    pB += eB0.x * Ta.x + eB0.y * Ta.y + eB0.z * Ta.z + eB0.w * Ta.w;
    pB += eB1.x * Tc.x + eB1.y * Tc.y + eB1.z * Tc.z + eB1.w * Tc.w;
    pA += __shfl_xor(pA, 1, 64); pA += __shfl_xor(pA, 2, 64); pA += __shfl_xor(pA, 4, 64);
    pB += __shfl_xor(pB, 1, 64); pB += __shfl_xor(pB, 2, 64); pB += __shfl_xor(pB, 4, 64);
    const float sA = pA * scale;
    const float sB = hasB ? pB * scale : -INFINITY;
    const float mn = fmaxf(m, fmaxf(sA, sB));
    const float corr = __expf(m - mn);   // exp(-inf)=0 on first iteration
    const float wA = __expf(sA - mn);
    const float wB = __expf(sB - mn);
    m = mn;
    den = den * corr + wA + wB;
    ax = ax * corr + wA * bf2f(vAu.x) + wB * bf2f(vBu.x);
    ay = ay * corr + wA * bf2f(vAu.y) + wB * bf2f(vBu.y);
    az = az * corr + wA * bf2f(vAu.z) + wB * bf2f(vBu.z);
    aw = aw * corr + wA * bf2f(vAu.w) + wB * bf2f(vBu.w);
    G[0] = G[0] * corr + wA * eA0.x + wB * eB0.x;
    G[1] = G[1] * corr + wA * eA0.y + wB * eB0.y;
    G[2] = G[2] * corr + wA * eA0.z + wB * eB0.z;
    G[3] = G[3] * corr + wA * eA0.w + wB * eB0.w;
    G[4] = G[4] * corr + wA * eA1.x + wB * eB1.x;
    G[5] = G[5] * corr + wA * eA1.y + wB * eB1.y;
    G[6] = G[6] * corr + wA * eA1.z + wB * eB1.z;
    G[7] = G[7] * corr + wA * eA1.w + wB * eB1.w;
  }
  float ex = 0.f, ey = 0.f, ez = 0.f, ew = 0.f;
#pragma unroll
  for (int c8 = 0; c8 < 8; ++c8) {
#pragma unroll
    for (int i = 0; i < 8; ++i) {
      const float Gc = __shfl(G[i], g * 8 + c8, 64);
      const int c = c8 * 8 + i;
      const float4 w4 = *(const float4*)(We + (size_t)c * 256 + lane * 4);
      ex = fmaf(Gc, w4.x, ex); ey = fmaf(Gc, w4.y, ey);
      ez = fmaf(Gc, w4.z, ez); ew = fmaf(Gc, w4.w, ew);
    }
  }
  const float inv = 1.f / (den + 1e-9f);
  float4 o;
  o.x = (ax + ex) * inv; o.y = (ay + ey) * inv;
  o.z = (az + ez) * inv; o.w = (aw + ew) * inv;
  *(float4*)(msg + (size_t)wv * 256 + lane * 4) = o;
}

// ============ residual add + LayerNorm ============
__global__ __launch_bounds__(256)
void add_ln_k(float* __restrict__ x, const float* __restrict__ add, int Nn)
{
  const int wv = (blockIdx.x * blockDim.x + threadIdx.x) >> 6;
  if (wv >= Nn) return;
  const int lane = threadIdx.x & 63;
  float4 xv = *(const float4*)(x + (size_t)wv * 256 + lane * 4);
  float4 av = *(const float4*)(add + (size_t)wv * 256 + lane * 4);
  float4 y;
  y.x = xv.x + av.x; y.y = xv.y + av.y; y.z = xv.z + av.z; y.w = xv.w + av.w;
  float s = y.x + y.y + y.z + y.w;
#pragma unroll
  for (int msk = 1; msk < 64; msk <<= 1) s += __shfl_xor(s, msk, 64);
  const float mean = s * (1.f / 256.f);
  float4 d;
  d.x = y.x - mean; d.y = y.y - mean; d.z = y.z - mean; d.w = y.w - mean;
  float sq = d.x*d.x + d.y*d.y + d.z*d.z + d.w*d.w;
#pragma unroll
  for (int msk = 1; msk < 64; msk <<= 1) sq += __shfl_xor(sq, msk, 64);
  const float r = rsqrtf(sq * (1.f / 256.f) + 1e-5f);
  float4 o;
  o.x = d.x * r; o.y = d.y * r; o.z = d.z * r; o.w = d.w * r;
  *(float4*)(x + (size_t)wv * 256 + lane * 4) = o;
}

// ============ utility / CSR kernels ============
__global__ void copy_f4_k(const float4* __restrict__ s, float4* __restrict__ d, int n4) {
  int i = blockIdx.x * blockDim.x + threadIdx.x;
  if (i < n4) d[i] = s[i];
}
__global__ void zero4_k(int* p, int n) {
  int i = blockIdx.x * blockDim.x + threadIdx.x;
  if (i < n) p[i] = 0;
}
__global__ void hist4_k(const int* d0, const int* d1, const int* d2, const int* d3,
                        int E0, int E1, int E2, int E3, int* cnt, int Nn) {
  const int s = blockIdx.y;
  const int* d = (s == 0) ? d0 : (s == 1) ? d1 : (s == 2) ? d2 : d3;
  const int E = (s == 0) ? E0 : (s == 1) ? E1 : (s == 2) ? E2 : E3;
  int e = blockIdx.x * 256 + threadIdx.x;
  if (e < E) atomicAdd(&cnt[s * Nn + d[e]], 1);
}
__global__ __launch_bounds__(256)
void scan4_k(const int* __restrict__ cnt, int* __restrict__ offs, int* __restrict__ cursor, int Nn)
{
  __shared__ int sums[256];
  const int s = blockIdx.x;
  const int t = threadIdx.x;
  const int* c = cnt + (size_t)s * Nn;
  int* o = offs + (size_t)s * (Nn + 1);
  int* cur = cursor + (size_t)s * Nn;
  const int chunk = (Nn + 255) / 256;
  const int base = t * chunk;
  int sl = 0;
  for (int i = 0; i < chunk; ++i) {
    int idx = base + i;
    if (idx < Nn) sl += c[idx];
  }
  sums[t] = sl;
  __syncthreads();
  for (int off = 1; off < 256; off <<= 1) {
    int val = (t >= off) ? sums[t - off] : 0;
    __syncthreads();
    sums[t] += val;
    __syncthreads();
  }
  int run = (t == 0) ? 0 : sums[t - 1];
  for (int i = 0; i < chunk; ++i) {
    int idx = base + i;
    if (idx < Nn) { o[idx] = run; cur[idx] = run; run += c[idx]; }
  }
  if (t == 255) o[Nn] = run;
}
__global__ void scatter4_k(const int* d0, const int* d1, const int* d2, const int* d3,
                           int E0, int E1, int E2, int E3, int* cursor,
                           int* s0, int* s1, int* s2, int* s3, int Nn) {
  const int s = blockIdx.y;
  const int* d = (s == 0) ? d0 : (s == 1) ? d1 : (s == 2) ? d2 : d3;
  int* so = (s == 0) ? s0 : (s == 1) ? s1 : (s == 2) ? s2 : s3;
  const int E = (s == 0) ? E0 : (s == 1) ? E1 : (s == 2) ? E2 : E3;
  int e = blockIdx.x * 256 + threadIdx.x;
  if (e < E) {
    int pos = atomicAdd(&cursor[s * Nn + d[e]], 1);
    so[pos] = e;
  }
}

// ============ host orchestration ============
extern "C" void kernel_launch(void* const* d_in, const int* in_sizes, int n_in,
                              void* d_out, int out_size, void* d_ws, size_t ws_size,
                              hipStream_t stream)
{
  (void)n_in; (void)ws_size;
  const float* afl = (const float*)d_in[0];
  const float* afr = (const float*)d_in[1];
  const float* eaA[4] = {(const float*)d_in[2], (const float*)d_in[3],
                         (const float*)d_in[4], (const float*)d_in[5]};
  const int* eiA[4] = {(const int*)d_in[6], (const int*)d_in[7],
                       (const int*)d_in[8], (const int*)d_in[9]};
  const float* Wq  = (const float*)d_in[10];
  const float* Wk  = (const float*)d_in[11];
  const float* Wv  = (const float*)d_in[12];
  const float* Wvv = Wv;
  const float* We  = (const float*)d_in[13];
  const float* Wo  = (const float*)d_in[14];
  const float* fw1 = (const float*)d_in[15];
  const float* fb1 = (const float*)d_in[16];
  const float* fw2 = (const float*)d_in[17];
  const float* fb2 = (const float*)d_in[18];
  const float* hw1 = (const float*)d_in[19];
  const float* hb1 = (const float*)d_in[20];
  const float* hw2 = (const float*)d_in[21];
  const float* hb2 = (const float*)d_in[22];

  const int Nn = in_sizes[0] / 256;
  const int E[4] = {in_sizes[2] / 64, in_sizes[3] / 64, in_sizes[4] / 64, in_sizes[5] / 64};
  const int Mh = out_size / 14;
  const int astart = Nn - Mh;
  float* out = (float*)d_out;

  char* wsp = (char*)d_ws;
  auto alloc = [&](size_t bytes) -> void* {
    void* p = (void*)wsp;
    wsp += (bytes + 255) & ~(size_t)255;
    return p;
  };
  const size_t n256b = (size_t)Nn * 256 * sizeof(float);
  float* xl   = (float*)alloc(n256b);
  float* xr   = (float*)alloc(n256b);
  float* aggl = (float*)alloc(n256b);
  float* aggr = (float*)alloc(n256b);
  float* q    = (float*)alloc(n256b);
  float* msg  = (float*)alloc(n256b);
  unsigned short* kvb = (unsigned short*)alloc((size_t)Nn * 512 * sizeof(unsigned short));
  float* Tb   = (float*)alloc((size_t)Nn * 512 * sizeof(float));  // T, then FFN hidden
  unsigned short* BTqkv = (unsigned short*)alloc((size_t)8 * 768 * 256 * 2);
  unsigned short* BTo   = (unsigned short*)alloc((size_t)8 * 256 * 256 * 2);
  unsigned short* BTf1  = (unsigned short*)alloc((size_t)4 * 512 * 256 * 2);
  unsigned short* BTf2  = (unsigned short*)alloc((size_t)4 * 256 * 512 * 2);
  unsigned short* BTh1  = (unsigned short*)alloc((size_t)256 * 256 * 2);
  float* WeT8 = (float*)alloc((size_t)8 * 16384 * sizeof(float));
  int* offs4  = (int*)alloc((size_t)4 * (Nn + 1) * sizeof(int));
  int* cnt4   = (int*)alloc((size_t)4 * Nn * sizeof(int));
  int* cur4   = (int*)alloc((size_t)4 * Nn * sizeof(int));
  int* sortA[4];
  for (int s = 0; s < 4; ++s) sortA[s] = (int*)alloc((size_t)E[s] * sizeof(int));

  const dim3 B256(256);
  const int wgNodes = (Nn * 64 + 255) / 256;
  const int maxE = E[0] > E[1] ? (E[0] > E[2] ? (E[0] > E[3] ? E[0] : E[3]) : (E[2] > E[3] ? E[2] : E[3]))
                               : (E[1] > E[2] ? (E[1] > E[3] ? E[1] : E[3]) : (E[2] > E[3] ? E[2] : E[3]));

  // ---- init x, CSR, weight conversion ----
  {
    int n4 = Nn * 64;
    copy_f4_k<<<dim3((n4 + 255) / 256), B256, 0, stream>>>((const float4*)afl, (float4*)xl, n4);
    copy_f4_k<<<dim3((n4 + 255) / 256), B256, 0, stream>>>((const float4*)afr, (float4*)xr, n4);
  }
  zero4_k<<<dim3((4 * Nn + 255) / 256), B256, 0, stream>>>(cnt4, 4 * Nn);
  {
    const int* dp[4] = {eiA[0] + E[0], eiA[1] + E[1], eiA[2] + E[2], eiA[3] + E[3]};
    dim3 gh((maxE + 255) / 256, 4);
    hist4_k<<<gh, B256, 0, stream>>>(dp[0], dp[1], dp[2], dp[3], E[0], E[1], E[2], E[3], cnt4, Nn);
    scan4_k<<<dim3(4), B256, 0, stream>>>(cnt4, offs4, cur4, Nn);
    scatter4_k<<<gh, B256, 0, stream>>>(dp[0], dp[1], dp[2], dp[3], E[0], E[1], E[2], E[3],
                                        cur4, sortA[0], sortA[1], sortA[2], sortA[3], Nn);
  }
  {
    dim3 g256((256 * 256 + 255) / 256, 8);
    tc_k<<<g256, B256, 0, stream>>>(Wq, BTqkv, 256, 256, 65536, 768 * 256, 0);
    tc_k<<<g256, B256, 0, stream>>>(Wk, BTqkv, 256, 256, 65536, 768 * 256, 256);
    tc_k<<<g256, B256, 0, stream>>>(Wvv, BTqkv, 256, 256, 65536, 768 * 256, 512);
    tc_k<<<g256, B256, 0, stream>>>(Wo, BTo, 256, 256, 65536, 65536, 0);
    dim3 gf((512 * 256 + 255) / 256, 4);
    tc_k<<<gf, B256, 0, stream>>>(fw1, BTf1, 256, 512, 131072, 131072, 0);
    tc_k<<<gf, B256, 0, stream>>>(fw2, BTf2, 512, 256, 131072, 131072, 0);
    tc_k<<<dim3((65536 + 255) / 256, 1), B256, 0, stream>>>(hw1, BTh1, 256, 256, 65536, 65536, 0);
    weT_k<<<dim3((16384 + 255) / 256, 8), B256, 0, stream>>>(We, WeT8);
  }

  auto mfma = [&](const float* A, const unsigned short* BT, const float* bias,
                  float* Cf, unsigned short* Cb, int M, int N, int K, int S, int ldf, int ldb,
                  bool acc, bool biasf, bool gelu) {
    dim3 g(M / 128, N / 128);
    if (acc)             gemm_mfma_k<true,  false, false><<<g, B256, 0, stream>>>(A, BT, bias, Cf, Cb, M, N, K, S, ldf, ldb);
    else if (biasf && gelu) gemm_mfma_k<false, true, true ><<<g, B256, 0, stream>>>(A, BT, bias, Cf, Cb, M, N, K, S, ldf, ldb);
    else if (biasf)      gemm_mfma_k<false, true, false><<<g, B256, 0, stream>>>(A, BT, bias, Cf, Cb, M, N, K, S, ldf, ldb);
    else                 gemm_mfma_k<false, false, false><<<g, B256, 0, stream>>>(A, BT, bias, Cf, Cb, M, N, K, S, ldf, ldb);
  };

  auto run_attn = [&](int l, int i, const float* xq, const float* xk, float* agg, bool acc) {
    const int idx = l * 4 + i;
    const unsigned short* bt = BTqkv + (size_t)idx * 768 * 256;
    if (xq == xk) {
      mfma(xq, bt, nullptr, q, kvb, Nn, 768, 256, 256, 256, 512, false, false, false);
    } else {
      mfma(xq, bt, nullptr, q, nullptr, Nn, 256, 256, 256, 256, 0, false, false, false);
      mfma(xk, bt + 256 * 256, nullptr, nullptr, kvb, Nn, 512, 256, 0, 0, 512, false, false, false);
    }
    tproj_k<<<dim3(wgNodes), B256, 0, stream>>>(q, WeT8 + (size_t)idx * 16384, Tb, Nn);
    edge_attn_k<<<dim3(wgNodes), B256, 0, stream>>>(offs4 + (size_t)i * (Nn + 1), sortA[i], eiA[i],
                                                    eaA[i], Tb, q, kvb,
                                                    We + (size_t)idx * 16384, msg, Nn);
    mfma(msg, BTo + (size_t)idx * 65536, nullptr, agg, nullptr, Nn, 256, 256, 256, 256, 0,
         acc, false, false);
  };

  const int L = 2;
  for (int l = 0; l < L; ++l) {
    run_attn(l, 0, xl, xl, aggl, false);
    run_attn(l, 3, xl, xr, aggl, true);
    run_attn(l, 1, xr, xr, aggr, false);
    run_attn(l, 2, xr, xl, aggr, true);
    add_ln_k<<<dim3(wgNodes), B256, 0, stream>>>(xl, aggl, Nn);
    add_ln_k<<<dim3(wgNodes), B256, 0, stream>>>(xr, aggr, Nn);
    for (int s2 = 0; s2 < 2; ++s2) {
      float* x = s2 ? xr : xl;
      const int fi = l * 2 + s2;
      mfma(x, BTf1 + (size_t)fi * 131072, fb1 + (size_t)fi * 512, Tb, nullptr,
           Nn, 512, 256, 512, 512, 0, false, true, true);
      mfma(Tb, BTf2 + (size_t)fi * 131072, fb2 + (size_t)fi * 256, q, nullptr,
           Nn, 256, 512, 256, 256, 0, false, true, false);
      add_ln_k<<<dim3(wgNodes), B256, 0, stream>>>(x, q, Nn);
    }
  }
  // heads: gelu(x@hw1+hb1) @ hw2 + hb2
  mfma(xl + (size_t)astart * 256, BTh1, hb1, msg, nullptr, Mh, 256, 256, 256, 256, 0, false, true, true);
  gemm_k<false, true, false><<<dim3(Mh / 128, 1), B256, 0, stream>>>(msg, hw2, hb2, out, Mh, 7, 256);
  mfma(xr + (size_t)astart * 256, BTh1, hb1, msg, nullptr, Mh, 256, 256, 256, 256, 0, false, true, true);
  gemm_k<false, true, false><<<dim3(Mh / 128, 1), B256, 0, stream>>>(msg, hw2, hb2, out + (size_t)Mh * 7, Mh, 7, 256);
}